// Round 6
// baseline (438.112 us; speedup 1.0000x reference)
//
#include <hip/hip_runtime.h>

// SpikeLayer: V_t = reset(V_{t-1} + I_t), reset(x) = (|x|>1 ? 0 : x)
// inputs: [T*B, D] fp32, T=16, B=512, D=8192. out_t = V_t.
// Logical traffic 512 MB; ~81 us floor at 6.3 TB/s copy rate.
//
// R6: clean A/B of non-temporal stores on the proven R5 structure.
// Evidence: FETCH_SIZE=131MB of a 256MB input (R0) -> half the input is
// already L3-resident across iterations; the write-once output's
// write-allocations are what evict the other half. nt stores keep the
// 262MB write stream out of L3 so the input (256MB = exactly L3 size)
// can stay resident -> HBM demand becomes write-dominated.
// (R2's nt regression was confounded: it also halved run length and
// doubled stream count, which R4 showed costs ~20%.)
// Loads stay temporal: input is re-read every bench iteration.

typedef float f32x4 __attribute__((ext_vector_type(4)));

constexpr int TIMES = 16;
constexpr int K = 8;          // f32x4 columns per thread
constexpr int THREADS = 512;  // block covers THREADS*K = 4096 f32x4 = 64 KB/slice
constexpr long long STEP_F4 = (512LL * 8192LL) / 4;  // f32x4 per t-slice = 1048576

__device__ __forceinline__ void step_reset(f32x4& V, f32x4 I) {
    V += I;
    V.x = (fabsf(V.x) > 1.0f) ? 0.0f : V.x;
    V.y = (fabsf(V.y) > 1.0f) ? 0.0f : V.y;
    V.z = (fabsf(V.z) > 1.0f) ? 0.0f : V.z;
    V.w = (fabsf(V.w) > 1.0f) ? 0.0f : V.w;
}

__global__ __launch_bounds__(THREADS) void SpikeLayer_88553635709313_kernel(
    const f32x4* __restrict__ in, f32x4* __restrict__ out) {
    const long long base =
        (long long)blockIdx.x * (THREADS * K) + threadIdx.x;  // k=0 column
    const f32x4* __restrict__ ip = in + base;
    f32x4* __restrict__ op = out + base;

    f32x4 V[K];
#pragma unroll
    for (int k = 0; k < K; ++k) V[k] = (f32x4)0.0f;

    for (int t = 0; t < TIMES; ++t) {
        const long long toff = (long long)t * STEP_F4;
        f32x4 I[K];
        // 8 back-to-back wave-loads: one contiguous 64-KB block-run per slice.
#pragma unroll
        for (int k = 0; k < K; ++k) I[k] = ip[toff + k * THREADS];
#pragma unroll
        for (int k = 0; k < K; ++k) {
            step_reset(V[k], I[k]);
            __builtin_nontemporal_store(V[k], &op[toff + k * THREADS]);
        }
    }
}

extern "C" void kernel_launch(void* const* d_in, const int* in_sizes, int n_in,
                              void* d_out, int out_size, void* d_ws, size_t ws_size,
                              hipStream_t stream) {
    const f32x4* in = (const f32x4*)d_in[0];
    f32x4* out = (f32x4*)d_out;
    const int blocks = (int)(STEP_F4 / (THREADS * K));  // 256
    SpikeLayer_88553635709313_kernel<<<blocks, THREADS, 0, stream>>>(in, out);
}